// Round 14
// baseline (202.883 us; speedup 1.0000x reference)
//
#include <hip/hip_runtime.h>
#include <math.h>

#define DPI 3.141592653589793238462643383279502884

// ---------------- persistent (input-independent) Wigner tables ----------------
__device__ float g_Deff[1040384];  // [mm<127][t<128][l<64]  (mm-contiguous for ct_mid)
__device__ float g_Dinv[520192];   // [mm<127][l<64][t<64]
__device__ int g_wig_done = 0;

// ---------------- device helpers ----------------
__device__ __forceinline__ float gelu_tanh(float v) {
  float u = 0.7978845608028654f * (v + 0.044715f * v * v * v);
  return 0.5f * v * (1.0f + tanhf(u));
}

#define CN255F ((float)(-2.0 * DPI / 255.0))
#define CN127F ((float)(2.0 * DPI / 127.0))

// ======================= dft block =======================
// ftm planes laid out [mi<64][t<128][c<64] (mi-contiguous for ct_mid).
__device__ __forceinline__ void dft_block(int t, int ph, int mh, int tid,
                                          const float* __restrict__ x,
                                          float* __restrict__ Are, float* __restrict__ Aim,
                                          float* __restrict__ Bre, float* __restrict__ Bim,
                                          char* sm) {
  float* xs_ = (float*)sm;  // [64][64] 16 KB
  float* ore = ph ? Bre : Are;
  float* oim = ph ? Bim : Aim;
  int pbase = ph * 128;
  int Ktot = ph ? 127 : 128;
  int cg_ = tid & 15, mg = tid >> 4;
  float wr[2], wi[2], rc[2], rs[2];
#pragma unroll
  for (int j = 0; j < 2; ++j) {
    int m = mh * 32 + mg * 2 + j;
    __sincosf(CN255F * (float)m, &rs[j], &rc[j]);
    int r0 = (m * pbase) % 255;
    __sincosf(CN255F * (float)r0, &wi[j], &wr[j]);
  }
  float accr[2][4], acci[2][4];
#pragma unroll
  for (int j = 0; j < 2; ++j)
#pragma unroll
    for (int q = 0; q < 4; ++q) { accr[j][q] = 0.f; acci[j][q] = 0.f; }
  for (int k0 = 0; k0 < Ktot; k0 += 64) {
    int kn = (Ktot - k0 < 64) ? Ktot - k0 : 64;
    __syncthreads();
    {
      const float4* src = (const float4*)(x + ((size_t)t * 255 + pbase + k0) * 64);
      float4* dst = (float4*)xs_;
      int lim = kn * 16;
#pragma unroll
      for (int q = 0; q < 4; ++q) {
        int fidx = tid + q * 256;
        if (fidx < lim) dst[fidx] = src[fidx];
      }
    }
    __syncthreads();
#pragma unroll 2
    for (int k = 0; k < kn; ++k) {
      float4 xv = *(const float4*)&xs_[k * 64 + cg_ * 4];
      float xv4[4] = {xv.x, xv.y, xv.z, xv.w};
#pragma unroll
      for (int j = 0; j < 2; ++j) {
#pragma unroll
        for (int q = 0; q < 4; ++q) {
          accr[j][q] = fmaf(xv4[q], wr[j], accr[j][q]);
          acci[j][q] = fmaf(xv4[q], wi[j], acci[j][q]);
        }
        float nw = wr[j] * rc[j] - wi[j] * rs[j];
        wi[j] = fmaf(wr[j], rs[j], wi[j] * rc[j]);
        wr[j] = nw;
      }
    }
  }
#pragma unroll
  for (int j = 0; j < 2; ++j) {
    int mi = mh * 32 + mg * 2 + j;
    size_t ob = ((size_t)mi * 128 + t) * 64 + cg_ * 4;
    *(float4*)(ore + ob) = make_float4(accr[j][0], accr[j][1], accr[j][2], accr[j][3]);
    *(float4*)(oim + ob) = make_float4(acci[j][0], acci[j][1], acci[j][2], acci[j][3]);
  }
}

// ======================= wigner (memoized) =======================
__device__ __forceinline__ void wigner_block(int wb, int tid, char* sm) {
  if (__hip_atomic_load(&g_wig_done, __ATOMIC_RELAXED, __HIP_MEMORY_SCOPE_AGENT)) return;
  float* LF = (float*)sm;             // [128] log(n!)
  double* red = (double*)(sm + 512);  // [64]
  float* clf = (float*)(sm + 1024);   // [64]
  int mode = (wb < 128) ? 0 : 1;
  int t, mm;
  if (mode == 0) { t = wb; mm = tid; }
  else { mm = wb - 128; t = (tid < 64) ? tid : 63; }
  if (tid < 64) clf[tid] = (float)(-sqrt((2.0 * tid + 1.0) / (4.0 * DPI)));
  if (tid < 128) LF[tid] = (tid == 0) ? 0.f : logf((float)tid);
  __syncthreads();
  for (int s = 1; s < 128; s <<= 1) {
    float add = (tid < 128 && tid >= s) ? LF[tid - s] : 0.f;
    __syncthreads();
    if (tid < 128) LF[tid] += add;
    __syncthreads();
  }
  double denomN = (mode == 0) ? 255.0 : 127.0;
  double beta = (2.0 * t + 1.0) * DPI / denomN;
  float coeff = 1.0f;
  if (mode == 0) {
    if (tid < 63) {
      int k = 2 * (tid + 1);
      red[tid] = 8.0 * cos((double)k * beta) / (1.0 - (double)k * (double)k);
    } else if (tid == 63) {
      red[63] = 4.0;
    }
    __syncthreads();
    for (int s = 32; s > 0; s >>= 1) {
      if (tid < s) red[tid] += red[tid + s];
      __syncthreads();
    }
    double s = red[0] / 255.0;
    if (t == 127) s *= 0.5;
    coeff = (float)(s * (2.0 * DPI / 255.0));
  }
  bool active = (mode == 0) ? (tid < 127) : (tid < 64);
  if (!active) return;
  int m = mm - 63;
  double chd, shd;
  sincos(0.5 * beta, &shd, &chd);
  float cbf = (float)cos(beta);
  float chf = (float)chd, shf = (float)shd;
  int am = (m < 0) ? -m : m;
  int l0v = (am > 1) ? am : 1;
  float seed;
  if (m == 0) {
    seed = -1.4142135623730951f * shf * chf;
  } else {
    int j = am;
    float lch = logf(chf), lsh = logf(shf);
    float e0 = 0.5f * (LF[2 * j] - LF[j - 1] - LF[j + 1]);
    float expo = (m >= 1) ? e0 + (float)(j - 1) * lch + (float)(j + 1) * lsh
                          : e0 + (float)(j + 1) * lch + (float)(j - 1) * lsh;
    float sv = __expf(expo);
    seed = (m >= 1 && ((m + 1) & 1)) ? -sv : sv;
  }
  float dl = seed, dm1 = 0.0f, S_cur = 0.0f;
  float mf = (float)m;
  for (int l = 0; l < 64; ++l) {
    float val = 0.0f;
    if (l >= l0v) {
      val = dl * coeff * clf[l];
      float Ld = (float)l, lp = Ld + 1.0f;
      float S_next = sqrtf((lp * lp - mf * mf) * (lp * lp - 1.0f));
      float num1 = (2.0f * Ld + 1.0f) * (Ld * lp * cbf + mf);
      float dn = (num1 * dl - lp * S_cur * dm1) / (Ld * S_next);
      dm1 = dl; dl = dn; S_cur = S_next;
    }
    if (mode == 0) g_Deff[((size_t)mm * 128 + t) * 64 + l] = val;
    else g_Dinv[((size_t)mm * 64 + l) * 64 + t] = val;
  }
}

// ======================= setup blocks (hosted in ct_pre) =======================
// A2T layout: [l<64][o<64][i<64] float2 — per-thread-contiguous for ct_mid stage B.
__device__ __forceinline__ void a2_block(int l, int tid, const float* __restrict__ temb,
                                         const float* __restrict__ trw, const float* __restrict__ trb,
                                         const float* __restrict__ tiw, const float* __restrict__ tib,
                                         const float* __restrict__ scw, const float* __restrict__ swr,
                                         const float* __restrict__ swi, float2* __restrict__ A2T,
                                         char* sm) {
  float* fb1 = (float*)sm;
  float* fb2 = (float*)(sm + 1024);
  fb1[tid] = temb[tid] * trw[tid * 64 + l];
  fb2[tid] = temb[tid] * tiw[tid * 64 + l];
  __syncthreads();
  for (int s = 128; s > 0; s >>= 1) {
    if (tid < s) { fb1[tid] += fb1[tid + s]; fb2[tid] += fb2[tid + s]; }
    __syncthreads();
  }
  float tr = fb1[0] + trb[l], ti = fb2[0] + tib[l];
  __syncthreads();  // fb region dead; overlay transpose tiles
  float* tre = (float*)sm;             // [64][65] 16640 B
  float* tim = (float*)(sm + 16640);   // [64][65]
  int o = tid & 63, iq = tid >> 6;
#pragma unroll 4
  for (int i = iq * 16; i < iq * 16 + 16; ++i) {
    int idx = (l * 64 + i) * 64 + o;
    float r = swr[idx], s2 = swi[idx];
    tre[i * 65 + o] = scw[i * 64 + o] + tr * r - ti * s2;
    tim[i * 65 + o] = tr * s2 + ti * r;
  }
  __syncthreads();
  for (int e = tid; e < 4096; e += 256) {
    int oo = e >> 6, ii = e & 63;
    A2T[((size_t)l * 64 + oo) * 64 + ii] = make_float2(tre[ii * 65 + oo], tim[ii * 65 + oo]);
  }
}

// one block: tv[0..127], MmT[o][i], bias2[64] — LDS-staged, ILP'd loads
__device__ __forceinline__ void mstv_block(int tid, const float* __restrict__ temb,
                                           const float* __restrict__ stw, const float* __restrict__ stb,
                                           const float* __restrict__ c1w, const float* __restrict__ c1b,
                                           const float* __restrict__ sweight,
                                           float* __restrict__ tv, float* __restrict__ MmT,
                                           float* __restrict__ bias2, char* sm) {
  float* temb_s = (float*)sm;           // [256]   1 KB
  float* swt = (float*)(sm + 1024);     // [64][64] 16 KB (sweight)
  float* c1s = (float*)(sm + 17408);    // [64][65] 16.25 KB (c1w, padded)
  float* tvo_s = (float*)(sm + 34048);  // [64]
  if (tid < 64) ((float4*)temb_s)[tid] = ((const float4*)temb)[tid];
  for (int q = tid; q < 1024; q += 256) ((float4*)swt)[q] = ((const float4*)sweight)[q];
  for (int e = tid; e < 4096; e += 256) c1s[(e >> 6) * 65 + (e & 63)] = c1w[e];
  __syncthreads();
  if (tid < 128) {
    float a0 = 0.f, a1 = 0.f, a2 = 0.f, a3 = 0.f;
#pragma unroll 8
    for (int k = 0; k < 256; k += 4) {
      a0 = fmaf(temb_s[k],     stw[k * 128 + tid],       a0);
      a1 = fmaf(temb_s[k + 1], stw[(k + 1) * 128 + tid], a1);
      a2 = fmaf(temb_s[k + 2], stw[(k + 2) * 128 + tid], a2);
      a3 = fmaf(temb_s[k + 3], stw[(k + 3) * 128 + tid], a3);
    }
    float tvv = a0 + a1 + a2 + a3 + stb[tid];
    tv[tid] = tvv;
    if (tid < 64) tvo_s[tid] = tvv;
  }
  __syncthreads();
  {
    int j = tid >> 2, ob = (tid & 3) * 16;
    float acc[16];
#pragma unroll
    for (int q = 0; q < 16; ++q) acc[q] = 0.f;
    for (int i = 0; i < 64; ++i) {
      float c = c1s[j * 65 + i];
#pragma unroll
      for (int q = 0; q < 16; ++q) acc[q] = fmaf(c, swt[i * 64 + ob + q], acc[q]);
    }
    // MmT[o][i] = tvo[o] * (c1w[i_row=j? ...]): original Mm[j][o]; transposed store.
#pragma unroll
    for (int q = 0; q < 16; ++q) MmT[(size_t)(ob + q) * 64 + j] = tvo_s[ob + q] * acc[q];
  }
  if (tid < 64) {
    float acc = 0.f;
#pragma unroll 4
    for (int i = 0; i < 64; ++i) acc = fmaf(c1b[i], swt[i * 64 + tid], acc);
    bias2[tid] = tvo_s[tid] * acc;
  }
}

// ======================= ct_pre: wigner + forward DFT + setup =======================
// grid 832: 0..254 wigner; 255..766 dft (XCD-paired mh); 767..830 a2; 831 mstv.
__global__ __launch_bounds__(256, 2) void ct_pre(
    const float* __restrict__ x, const float* __restrict__ temb,
    const float* __restrict__ trw, const float* __restrict__ trb,
    const float* __restrict__ tiw, const float* __restrict__ tib,
    const float* __restrict__ stw, const float* __restrict__ stb,
    const float* __restrict__ scw, const float* __restrict__ swr,
    const float* __restrict__ swi, const float* __restrict__ c1w,
    const float* __restrict__ c1b, const float* __restrict__ sweight,
    float2* __restrict__ A2T, float* __restrict__ MmT,
    float* __restrict__ bias2, float* __restrict__ tv,
    float* __restrict__ ftmA_re, float* __restrict__ ftmA_im,
    float* __restrict__ ftmB_re, float* __restrict__ ftmB_im) {
  __shared__ __align__(16) char sm[34304];
  int vb = blockIdx.x;
  int tid = threadIdx.x;
  if (vb < 255) wigner_block(vb, tid, sm);
  else if (vb < 767) {
    int u = vb - 255;                        // 0..511
    int g = u >> 4, mh = (u >> 3) & 1, s = u & 7;
    int tp = g * 8 + s;                      // 0..255
    dft_block(tp >> 1, tp & 1, mh, tid, x, ftmA_re, ftmA_im, ftmB_re, ftmB_im, sm);
  }
  else if (vb < 831) a2_block(vb - 767, tid, temb, trw, trb, tiw, tib, scw, swr, swi, A2T, sm);
  else mstv_block(tid, temb, stw, stb, c1w, c1b, sweight, tv, MmT, bias2, sm);
}

// ======================= ct_mid: fused projf + mix + proji, per (mm, oh), block 1024 =======================
// grid 256 linear: mm = (b>>4)*8 + (b&7), oh = (b>>3)&1; mm==127 -> idle.
__global__ __launch_bounds__(1024, 1) void ct_mid(
    const float* __restrict__ fAre, const float* __restrict__ fAim,
    const float* __restrict__ fBre, const float* __restrict__ fBim,
    const float2* __restrict__ A2T, const float* __restrict__ MmT,
    const float* __restrict__ scb, const float* __restrict__ bias2,
    float* __restrict__ fos_re, float* __restrict__ fos_im,
    float* __restrict__ foh_re, float* __restrict__ foh_im) {
  __shared__ __align__(16) char sm[98304];
  int b = blockIdx.x;
  int mm = (b >> 4) * 8 + (b & 7);
  int oh = (b >> 3) & 1;
  if (mm > 126) return;
  int tid = threadIdx.x;
  int mi = (mm >= 63) ? (mm - 63) : (63 - mm);
  float csign = (mm >= 63) ? 1.0f : -1.0f;

  float* fre_s = (float*)(sm);             // [128][64] 32 KB
  float* fim_s = (float*)(sm + 32768);     // [128][64] 32 KB
  float* Dt    = (float*)(sm + 65536);     // [128][64] 32 KB ([t][l])
  float* flm_re = (float*)(sm);            // [64][68] 17408 B (overlay)
  float* flm_im = (float*)(sm + 17408);    // [64][68]
  float* slS    = (float*)(sm + 34816);    // [64]
  float* sS_re  = (float*)(sm + 35072);    // [64][34]
  float* sS_im  = (float*)(sm + 43776);
  float* hS_re  = (float*)(sm + 52480);
  float* hS_im  = (float*)(sm + 61184);
  float* Dsh    = (float*)(sm + 69888);    // [64][64] 16 KB

  // Stage A staging: all streams fully contiguous (32 KB each)
  {
    const float4* pAre = (const float4*)fAre + (size_t)mi * 2048;
    const float4* pBre = (const float4*)fBre + (size_t)mi * 2048;
    const float4* pAim = (const float4*)fAim + (size_t)mi * 2048;
    const float4* pBim = (const float4*)fBim + (size_t)mi * 2048;
    const float4* pD = (const float4*)g_Deff + (size_t)mm * 2048;
    for (int e = tid; e < 2048; e += 1024) {
      float4 a = pAre[e];
      float4 bb = pBre[e];
      float4 a2i = pAim[e];
      float4 b2i = pBim[e];
      float4 d4 = pD[e];
      ((float4*)fre_s)[e] = make_float4(a.x + bb.x, a.y + bb.y, a.z + bb.z, a.w + bb.w);
      ((float4*)fim_s)[e] = make_float4(csign * (a2i.x + b2i.x), csign * (a2i.y + b2i.y),
                                        csign * (a2i.z + b2i.z), csign * (a2i.w + b2i.w));
      ((float4*)Dt)[e] = d4;
    }
  }
  __syncthreads();
  int cg = tid & 15, lw = tid >> 4;
  float ar[4], ai[4], sl = 0.f;
#pragma unroll
  for (int q = 0; q < 4; ++q) { ar[q] = 0.f; ai[q] = 0.f; }
#pragma unroll 4
  for (int k = 0; k < 128; ++k) {
    float4 fr4 = *(const float4*)&fre_s[k * 64 + cg * 4];
    float4 fi4 = *(const float4*)&fim_s[k * 64 + cg * 4];
    float dv = Dt[k * 64 + lw];
    float frv[4] = {fr4.x, fr4.y, fr4.z, fr4.w};
    float fiv[4] = {fi4.x, fi4.y, fi4.z, fi4.w};
    sl += dv;
#pragma unroll
    for (int q = 0; q < 4; ++q) {
      ar[q] = fmaf(dv, frv[q], ar[q]);
      ai[q] = fmaf(dv, fiv[q], ai[q]);
    }
  }
  __syncthreads();
  *(float4*)&flm_re[lw * 68 + cg * 4] = make_float4(ar[0], ar[1], ar[2], ar[3]);
  *(float4*)&flm_im[lw * 68 + cg * 4] = make_float4(ai[0], ai[1], ai[2], ai[3]);
  if (cg == 0) slS[lw] = sl;
  __syncthreads();

  // ---------------- Stage B: per-thread contiguous A2T/MmT streams ----------------
  {
    int lB = tid >> 4;
    int ov = tid & 15;
    int o0 = oh * 32 + ov * 2;
    const float2* a0p = &A2T[((size_t)lB * 64 + o0) * 64];
    const float2* a1p = &A2T[((size_t)lB * 64 + o0 + 1) * 64];
    const float* m0p = &MmT[(size_t)o0 * 64];
    const float* m1p = &MmT[(size_t)(o0 + 1) * 64];
    float sr0 = scb[o0], sr1 = scb[o0 + 1];
    float si0 = 0.f, si1 = 0.f, hr0 = 0.f, hr1 = 0.f, hi0 = 0.f, hi1 = 0.f;
#pragma unroll 8
    for (int i = 0; i < 64; ++i) {
      float fr = flm_re[lB * 68 + i];
      float fi = flm_im[lB * 68 + i];
      float2 a0 = a0p[i];
      float2 a1 = a1p[i];
      float m0 = m0p[i];
      float m1 = m1p[i];
      sr0 = fmaf(fr, a0.x, fmaf(-fi, a0.y, sr0));
      si0 = fmaf(fr, a0.y, fmaf(fi, a0.x, si0));
      sr1 = fmaf(fr, a1.x, fmaf(-fi, a1.y, sr1));
      si1 = fmaf(fr, a1.y, fmaf(fi, a1.x, si1));
      hr0 = fmaf(fr, m0, hr0);
      hi0 = fmaf(fi, m0, hi0);
      hr1 = fmaf(fr, m1, hr1);
      hi1 = fmaf(fi, m1, hi1);
    }
    if (mm == 63) {
      float sl63 = 255.0f * slS[lB];
      hr0 = fmaf(sl63, bias2[o0], hr0);
      hr1 = fmaf(sl63, bias2[o0 + 1], hr1);
    }
    int ob = ov * 2;
    sS_re[lB * 34 + ob] = sr0; sS_re[lB * 34 + ob + 1] = sr1;
    sS_im[lB * 34 + ob] = si0; sS_im[lB * 34 + ob + 1] = si1;
    hS_re[lB * 34 + ob] = hr0; hS_re[lB * 34 + ob + 1] = hr1;
    hS_im[lB * 34 + ob] = hi0; hS_im[lB * 34 + ob + 1] = hi1;
  }
  __syncthreads();

  for (int e = tid; e < 4096; e += 1024) {
    int r = e >> 6, tt = e & 63;
    Dsh[r * 64 + tt] = g_Dinv[((size_t)mm * 64 + r) * 64 + tt];
  }
  __syncthreads();
  {
    int cg2 = tid & 15, tg = tid >> 4;
    float as_r[2], as_i[2], ah_r[2], ah_i[2];
#pragma unroll
    for (int q = 0; q < 2; ++q) {
      as_r[q] = 0.f; as_i[q] = 0.f; ah_r[q] = 0.f; ah_i[q] = 0.f;
    }
#pragma unroll 4
    for (int l = 0; l < 64; ++l) {
      float dv = Dsh[l * 64 + tg];
      float2 s_r = *(const float2*)&sS_re[l * 34 + cg2 * 2];
      float2 s_i = *(const float2*)&sS_im[l * 34 + cg2 * 2];
      float2 h_r = *(const float2*)&hS_re[l * 34 + cg2 * 2];
      float2 h_i = *(const float2*)&hS_im[l * 34 + cg2 * 2];
      float srv[2] = {s_r.x, s_r.y}, siv[2] = {s_i.x, s_i.y};
      float hrv[2] = {h_r.x, h_r.y}, hiv[2] = {h_i.x, h_i.y};
#pragma unroll
      for (int q = 0; q < 2; ++q) {
        as_r[q] = fmaf(dv, srv[q], as_r[q]);
        as_i[q] = fmaf(dv, siv[q], as_i[q]);
        ah_r[q] = fmaf(dv, hrv[q], ah_r[q]);
        ah_i[q] = fmaf(dv, hiv[q], ah_i[q]);
      }
    }
    int c0 = oh * 32 + cg2 * 2;
    size_t ob = ((size_t)tg * 127 + mm) * 64 + c0;
    *(float2*)(fos_re + ob) = make_float2(as_r[0], as_r[1]);
    *(float2*)(fos_im + ob) = make_float2(as_i[0], as_i[1]);
    *(float2*)(foh_re + ob) = make_float2(ah_r[0], ah_r[1]);
    *(float2*)(foh_im + ob) = make_float2(ah_i[0], ah_i[1]);
  }
}

// ======================= ct_tail: fused inverse-DFT (full K) + epilogue =======================
// grid 256 linear: t = (b>>5)*8 + (b&7), q = (b>>3)&3.
__global__ __launch_bounds__(1024, 1) void ct_tail(
    const float* __restrict__ fos_re, const float* __restrict__ fos_im,
    const float* __restrict__ foh_re, const float* __restrict__ foh_im,
    const float* __restrict__ c2w, const float* __restrict__ c2b,
    const float* __restrict__ tv, const float* __restrict__ lns,
    const float* __restrict__ lnb, float* __restrict__ out) {
  __shared__ __align__(16) char smc[32768];
  float* fsr = (float*)(smc);
  float* fsi = (float*)(smc + 8192);
  float* fhr = (float*)(smc + 16384);
  float* fhi = (float*)(smc + 24576);
  float* hS   = (float*)(smc);           // [32][66] = 8448 B (overlay)
  float* c2wS = (float*)(smc + 8448);    // [64][64] = 16384 B

  int b = blockIdx.x;
  int t = (b >> 5) * 8 + (b & 7);
  int q = (b >> 3) & 3;
  int tid = threadIdx.x;
  int gpg = tid >> 5;        // 0..31
  int cg = tid & 31;         // 0..31
  int gp = q * 32 + gpg;     // 0..127 (127 invalid)
  bool valid = (gp < 127);
  int gpc = valid ? gp : 126;

  float rcv, rsv;
  __sincosf(CN127F * (float)gpc, &rsv, &rcv);
  float wcv, wsv;
  int r0 = (-63 * gpc) % 127;
  __sincosf(CN127F * (float)r0, &wsv, &wcv);

  float xacc[2] = {0.f, 0.f}, hacc[2] = {0.f, 0.f};
  for (int k0 = 0; k0 < 127; k0 += 32) {
    int kn = (127 - k0 < 32) ? 127 - k0 : 32;
    __syncthreads();
    for (int e = tid; e < 2048; e += 1024) {
      int a = e >> 9, rr = (e >> 4) & 31, c4 = e & 15;
      if (rr < kn) {
        size_t idx = ((size_t)t * 127 + k0 + rr) * 16 + c4;
        float4 v;
        float* dst;
        if (a == 0)      { v = ((const float4*)fos_re)[idx]; dst = fsr; }
        else if (a == 1) { v = ((const float4*)fos_im)[idx]; dst = fsi; }
        else if (a == 2) { v = ((const float4*)foh_re)[idx]; dst = fhr; }
        else             { v = ((const float4*)foh_im)[idx]; dst = fhi; }
        ((float4*)dst)[rr * 16 + c4] = v;
      }
    }
    __syncthreads();
#pragma unroll 2
    for (int k = 0; k < kn; ++k) {
      float2 sr = *(const float2*)&fsr[k * 64 + cg * 2];
      float2 si = *(const float2*)&fsi[k * 64 + cg * 2];
      float2 hr = *(const float2*)&fhr[k * 64 + cg * 2];
      float2 hi = *(const float2*)&fhi[k * 64 + cg * 2];
      xacc[0] = fmaf(sr.x, wcv, xacc[0]); xacc[0] = fmaf(si.x, -wsv, xacc[0]);
      xacc[1] = fmaf(sr.y, wcv, xacc[1]); xacc[1] = fmaf(si.y, -wsv, xacc[1]);
      hacc[0] = fmaf(hr.x, wcv, hacc[0]); hacc[0] = fmaf(hi.x, -wsv, hacc[0]);
      hacc[1] = fmaf(hr.y, wcv, hacc[1]); hacc[1] = fmaf(hi.y, -wsv, hacc[1]);
      float nw = wcv * rcv - wsv * rsv;
      wsv = fmaf(wcv, rsv, wsv * rcv);
      wcv = nw;
    }
  }
  __syncthreads();  // staging dead; epilogue overlays

  if (valid) {
    hS[gpg * 66 + cg * 2] = hacc[0];
    hS[gpg * 66 + cg * 2 + 1] = hacc[1];
  }
  for (int e = tid; e < 1024; e += 1024)
    ((float4*)c2wS)[e] = ((const float4*)c2w)[e];
  __syncthreads();

  if (valid) {
    int c0 = cg * 2;
    float a0 = c2b[c0] + tv[64 + c0];
    float a1 = c2b[c0 + 1] + tv[64 + c0 + 1];
#pragma unroll 8
    for (int i = 0; i < 64; ++i) {
      float hvi = hS[gpg * 66 + i];
      a0 = fmaf(hvi, c2wS[i * 64 + c0], a0);
      a1 = fmaf(hvi, c2wS[i * 64 + c0 + 1], a1);
    }
    float ssl = xacc[0] * xacc[0] + xacc[1] * xacc[1];
#pragma unroll
    for (int off = 16; off > 0; off >>= 1) ssl += __shfl_xor(ssl, off, 64);
    float inv = 1.0f / (sqrtf(ssl) + 1e-6f);
    float y0 = xacc[0] * inv + a0;
    float y1 = xacc[1] * inv + a1;
    float g0 = gelu_tanh(y0), g1 = gelu_tanh(y1);
    float ms = g0 + g1;
#pragma unroll
    for (int off = 16; off > 0; off >>= 1) ms += __shfl_xor(ms, off, 64);
    float mu = ms * (1.0f / 64.0f);
    float d0 = g0 - mu, d1 = g1 - mu;
    float vs = d0 * d0 + d1 * d1;
#pragma unroll
    for (int off = 16; off > 0; off >>= 1) vs += __shfl_xor(vs, off, 64);
    float rstd = rsqrtf(vs * (1.0f / 64.0f) + 1e-6f);
    size_t ob = ((size_t)t * 127 + gp) * 64 + c0;
    out[ob] = d0 * rstd * lns[c0] + lnb[c0];
    out[ob + 1] = d1 * rstd * lns[c0 + 1] + lnb[c0 + 1];
  }
  if (blockIdx.x == 0 && tid == 0)
    __hip_atomic_store(&g_wig_done, 1, __ATOMIC_RELAXED, __HIP_MEMORY_SCOPE_AGENT);
}

// ---------------- host launcher ----------------
extern "C" void kernel_launch(void* const* d_in, const int* in_sizes, int n_in,
                              void* d_out, int out_size, void* d_ws, size_t ws_size,
                              hipStream_t stream) {
  const float* x = (const float*)d_in[0];
  const float* temb = (const float*)d_in[1];
  const float* scw = (const float*)d_in[2];
  const float* scb = (const float*)d_in[3];
  const float* swr = (const float*)d_in[4];
  const float* swi = (const float*)d_in[5];
  const float* strw = (const float*)d_in[6];
  const float* strb = (const float*)d_in[7];
  const float* stiw = (const float*)d_in[8];
  const float* stib = (const float*)d_in[9];
  const float* c1w = (const float*)d_in[10];
  const float* c1b = (const float*)d_in[11];
  const float* stw = (const float*)d_in[12];
  const float* stb = (const float*)d_in[13];
  const float* sweight = (const float*)d_in[14];
  const float* c2w = (const float*)d_in[15];
  const float* c2b = (const float*)d_in[16];
  const float* lns = (const float*)d_in[17];
  const float* lnb = (const float*)d_in[18];
  float* out = (float*)d_out;

  char* base = (char*)d_ws;
  size_t off = 0;
  auto alloc = [&](size_t bytes) -> void* {
    void* p = base + off;
    off += (bytes + 255) & ~(size_t)255;
    return p;
  };
  float* tv = (float*)alloc(128 * sizeof(float));
  float* MmT = (float*)alloc(4096 * sizeof(float));        // [o][i]
  float* bias2 = (float*)alloc(64 * sizeof(float));
  float2* A2T = (float2*)alloc(262144 * sizeof(float2));   // [l][o][i]
  float* fos_re = (float*)alloc(520192 * sizeof(float));   // [t<64][mm][c]
  float* fos_im = (float*)alloc(520192 * sizeof(float));
  float* foh_re = (float*)alloc(520192 * sizeof(float));
  float* foh_im = (float*)alloc(520192 * sizeof(float));
  float* ftmA_re = (float*)alloc(524288 * sizeof(float));  // [mi<64][t<128][c]
  float* ftmA_im = (float*)alloc(524288 * sizeof(float));
  float* ftmB_re = (float*)alloc(524288 * sizeof(float));
  float* ftmB_im = (float*)alloc(524288 * sizeof(float));
  if (off > ws_size) return;  // workspace too small -> visible failure

  hipLaunchKernelGGL(ct_pre, dim3(832), dim3(256), 0, stream,
                     x, temb, strw, strb, stiw, stib, stw, stb,
                     scw, swr, swi, c1w, c1b, sweight,
                     A2T, MmT, bias2, tv,
                     ftmA_re, ftmA_im, ftmB_re, ftmB_im);
  hipLaunchKernelGGL(ct_mid, dim3(256), dim3(1024), 0, stream,
                     ftmA_re, ftmA_im, ftmB_re, ftmB_im,
                     A2T, MmT, scb, bias2,
                     fos_re, fos_im, foh_re, foh_im);
  hipLaunchKernelGGL(ct_tail, dim3(256), dim3(1024), 0, stream,
                     fos_re, fos_im, foh_re, foh_im,
                     c2w, c2b, tv, lns, lnb, out);
}

// Round 15
// 175.377 us; speedup vs baseline: 1.1568x; 1.1568x over previous
//
#include <hip/hip_runtime.h>
#include <math.h>

#define DPI 3.141592653589793238462643383279502884

// ---------------- persistent (input-independent) Wigner tables ----------------
__device__ float g_Deff[1040384];  // [mm<127][t<128][l<64]  (mm-contiguous for ct_mid)
__device__ float g_Dinv[520192];   // [mm<127][l<64][t<64]
__device__ int g_wig_done = 0;

// ---------------- device helpers ----------------
__device__ __forceinline__ float gelu_tanh(float v) {
  float u = 0.7978845608028654f * (v + 0.044715f * v * v * v);
  return 0.5f * v * (1.0f + tanhf(u));
}

#define CN255F ((float)(-2.0 * DPI / 255.0))
#define CN127F ((float)(2.0 * DPI / 127.0))

// ======================= dft block =======================
// ftm planes laid out [mi<64][t<128][c<64] (mi-contiguous for ct_mid).
__device__ __forceinline__ void dft_block(int t, int ph, int mh, int tid,
                                          const float* __restrict__ x,
                                          float* __restrict__ Are, float* __restrict__ Aim,
                                          float* __restrict__ Bre, float* __restrict__ Bim,
                                          char* sm) {
  float* xs_ = (float*)sm;  // [64][64] 16 KB
  float* ore = ph ? Bre : Are;
  float* oim = ph ? Bim : Aim;
  int pbase = ph * 128;
  int Ktot = ph ? 127 : 128;
  int cg_ = tid & 15, mg = tid >> 4;
  float wr[2], wi[2], rc[2], rs[2];
#pragma unroll
  for (int j = 0; j < 2; ++j) {
    int m = mh * 32 + mg * 2 + j;
    __sincosf(CN255F * (float)m, &rs[j], &rc[j]);
    int r0 = (m * pbase) % 255;
    __sincosf(CN255F * (float)r0, &wi[j], &wr[j]);
  }
  float accr[2][4], acci[2][4];
#pragma unroll
  for (int j = 0; j < 2; ++j)
#pragma unroll
    for (int q = 0; q < 4; ++q) { accr[j][q] = 0.f; acci[j][q] = 0.f; }
  for (int k0 = 0; k0 < Ktot; k0 += 64) {
    int kn = (Ktot - k0 < 64) ? Ktot - k0 : 64;
    __syncthreads();
    {
      const float4* src = (const float4*)(x + ((size_t)t * 255 + pbase + k0) * 64);
      float4* dst = (float4*)xs_;
      int lim = kn * 16;
#pragma unroll
      for (int q = 0; q < 4; ++q) {
        int fidx = tid + q * 256;
        if (fidx < lim) dst[fidx] = src[fidx];
      }
    }
    __syncthreads();
#pragma unroll 2
    for (int k = 0; k < kn; ++k) {
      float4 xv = *(const float4*)&xs_[k * 64 + cg_ * 4];
      float xv4[4] = {xv.x, xv.y, xv.z, xv.w};
#pragma unroll
      for (int j = 0; j < 2; ++j) {
#pragma unroll
        for (int q = 0; q < 4; ++q) {
          accr[j][q] = fmaf(xv4[q], wr[j], accr[j][q]);
          acci[j][q] = fmaf(xv4[q], wi[j], acci[j][q]);
        }
        float nw = wr[j] * rc[j] - wi[j] * rs[j];
        wi[j] = fmaf(wr[j], rs[j], wi[j] * rc[j]);
        wr[j] = nw;
      }
    }
  }
#pragma unroll
  for (int j = 0; j < 2; ++j) {
    int mi = mh * 32 + mg * 2 + j;
    size_t ob = ((size_t)mi * 128 + t) * 64 + cg_ * 4;
    *(float4*)(ore + ob) = make_float4(accr[j][0], accr[j][1], accr[j][2], accr[j][3]);
    *(float4*)(oim + ob) = make_float4(acci[j][0], acci[j][1], acci[j][2], acci[j][3]);
  }
}

// ======================= wigner (memoized) =======================
__device__ __forceinline__ void wigner_block(int wb, int tid, char* sm) {
  if (__hip_atomic_load(&g_wig_done, __ATOMIC_RELAXED, __HIP_MEMORY_SCOPE_AGENT)) return;
  float* LF = (float*)sm;             // [128] log(n!)
  double* red = (double*)(sm + 512);  // [64]
  float* clf = (float*)(sm + 1024);   // [64]
  int mode = (wb < 128) ? 0 : 1;
  int t, mm;
  if (mode == 0) { t = wb; mm = tid; }
  else { mm = wb - 128; t = (tid < 64) ? tid : 63; }
  if (tid < 64) clf[tid] = (float)(-sqrt((2.0 * tid + 1.0) / (4.0 * DPI)));
  if (tid < 128) LF[tid] = (tid == 0) ? 0.f : logf((float)tid);
  __syncthreads();
  for (int s = 1; s < 128; s <<= 1) {
    float add = (tid < 128 && tid >= s) ? LF[tid - s] : 0.f;
    __syncthreads();
    if (tid < 128) LF[tid] += add;
    __syncthreads();
  }
  double denomN = (mode == 0) ? 255.0 : 127.0;
  double beta = (2.0 * t + 1.0) * DPI / denomN;
  float coeff = 1.0f;
  if (mode == 0) {
    if (tid < 63) {
      int k = 2 * (tid + 1);
      red[tid] = 8.0 * cos((double)k * beta) / (1.0 - (double)k * (double)k);
    } else if (tid == 63) {
      red[63] = 4.0;
    }
    __syncthreads();
    for (int s = 32; s > 0; s >>= 1) {
      if (tid < s) red[tid] += red[tid + s];
      __syncthreads();
    }
    double s = red[0] / 255.0;
    if (t == 127) s *= 0.5;
    coeff = (float)(s * (2.0 * DPI / 255.0));
  }
  bool active = (mode == 0) ? (tid < 127) : (tid < 64);
  if (!active) return;
  int m = mm - 63;
  double chd, shd;
  sincos(0.5 * beta, &shd, &chd);
  float cbf = (float)cos(beta);
  float chf = (float)chd, shf = (float)shd;
  int am = (m < 0) ? -m : m;
  int l0v = (am > 1) ? am : 1;
  float seed;
  if (m == 0) {
    seed = -1.4142135623730951f * shf * chf;
  } else {
    int j = am;
    float lch = logf(chf), lsh = logf(shf);
    float e0 = 0.5f * (LF[2 * j] - LF[j - 1] - LF[j + 1]);
    float expo = (m >= 1) ? e0 + (float)(j - 1) * lch + (float)(j + 1) * lsh
                          : e0 + (float)(j + 1) * lch + (float)(j - 1) * lsh;
    float sv = __expf(expo);
    seed = (m >= 1 && ((m + 1) & 1)) ? -sv : sv;
  }
  float dl = seed, dm1 = 0.0f, S_cur = 0.0f;
  float mf = (float)m;
  for (int l = 0; l < 64; ++l) {
    float val = 0.0f;
    if (l >= l0v) {
      val = dl * coeff * clf[l];
      float Ld = (float)l, lp = Ld + 1.0f;
      float S_next = sqrtf((lp * lp - mf * mf) * (lp * lp - 1.0f));
      float num1 = (2.0f * Ld + 1.0f) * (Ld * lp * cbf + mf);
      float dn = (num1 * dl - lp * S_cur * dm1) / (Ld * S_next);
      dm1 = dl; dl = dn; S_cur = S_next;
    }
    if (mode == 0) g_Deff[((size_t)mm * 128 + t) * 64 + l] = val;
    else g_Dinv[((size_t)mm * 64 + l) * 64 + t] = val;
  }
}

// ======================= setup blocks (hosted in ct_pre) =======================
__device__ __forceinline__ void a2_block(int l, int tid, const float* __restrict__ temb,
                                         const float* __restrict__ trw, const float* __restrict__ trb,
                                         const float* __restrict__ tiw, const float* __restrict__ tib,
                                         const float* __restrict__ scw, const float* __restrict__ swr,
                                         const float* __restrict__ swi, float2* __restrict__ A2,
                                         char* sm) {
  float* fb1 = (float*)sm;
  float* fb2 = (float*)(sm + 1024);
  fb1[tid] = temb[tid] * trw[tid * 64 + l];
  fb2[tid] = temb[tid] * tiw[tid * 64 + l];
  __syncthreads();
  for (int s = 128; s > 0; s >>= 1) {
    if (tid < s) { fb1[tid] += fb1[tid + s]; fb2[tid] += fb2[tid + s]; }
    __syncthreads();
  }
  float tr = fb1[0] + trb[l], ti = fb2[0] + tib[l];
  int o = tid & 63, iq = tid >> 6;
#pragma unroll 4
  for (int i = iq * 16; i < iq * 16 + 16; ++i) {
    int idx = (l * 64 + i) * 64 + o;
    float r = swr[idx], s2 = swi[idx];
    A2[idx] = make_float2(scw[i * 64 + o] + tr * r - ti * s2, tr * s2 + ti * r);
  }
}

// one block: tv[0..127], Mm[64][64], bias2[64] — LDS-staged, ILP'd loads
__device__ __forceinline__ void mstv_block(int tid, const float* __restrict__ temb,
                                           const float* __restrict__ stw, const float* __restrict__ stb,
                                           const float* __restrict__ c1w, const float* __restrict__ c1b,
                                           const float* __restrict__ sweight,
                                           float* __restrict__ tv, float* __restrict__ Mm,
                                           float* __restrict__ bias2, char* sm) {
  float* temb_s = (float*)sm;           // [256]   1 KB
  float* swt = (float*)(sm + 1024);     // [64][64] 16 KB (sweight)
  float* c1s = (float*)(sm + 17408);    // [64][65] 16.25 KB (c1w, padded)
  float* tvo_s = (float*)(sm + 34048);  // [64]
  if (tid < 64) ((float4*)temb_s)[tid] = ((const float4*)temb)[tid];
  for (int q = tid; q < 1024; q += 256) ((float4*)swt)[q] = ((const float4*)sweight)[q];
  for (int e = tid; e < 4096; e += 256) c1s[(e >> 6) * 65 + (e & 63)] = c1w[e];
  __syncthreads();
  if (tid < 128) {
    float a0 = 0.f, a1 = 0.f, a2 = 0.f, a3 = 0.f;
#pragma unroll 8
    for (int k = 0; k < 256; k += 4) {
      a0 = fmaf(temb_s[k],     stw[k * 128 + tid],       a0);
      a1 = fmaf(temb_s[k + 1], stw[(k + 1) * 128 + tid], a1);
      a2 = fmaf(temb_s[k + 2], stw[(k + 2) * 128 + tid], a2);
      a3 = fmaf(temb_s[k + 3], stw[(k + 3) * 128 + tid], a3);
    }
    float tvv = a0 + a1 + a2 + a3 + stb[tid];
    tv[tid] = tvv;
    if (tid < 64) tvo_s[tid] = tvv;
  }
  __syncthreads();
  {
    int j = tid >> 2, ob = (tid & 3) * 16;
    float acc[16];
#pragma unroll
    for (int q = 0; q < 16; ++q) acc[q] = 0.f;
    for (int i = 0; i < 64; ++i) {
      float c = c1s[j * 65 + i];
#pragma unroll
      for (int q = 0; q < 16; ++q) acc[q] = fmaf(c, swt[i * 64 + ob + q], acc[q]);
    }
#pragma unroll
    for (int q = 0; q < 16; ++q) Mm[j * 64 + ob + q] = tvo_s[ob + q] * acc[q];
  }
  if (tid < 64) {
    float acc = 0.f;
#pragma unroll 4
    for (int i = 0; i < 64; ++i) acc = fmaf(c1b[i], swt[i * 64 + tid], acc);
    bias2[tid] = tvo_s[tid] * acc;
  }
}

// ======================= ct_pre: wigner + forward DFT + setup =======================
// grid 832: 0..254 wigner; 255..766 dft (XCD-paired mh); 767..830 a2; 831 mstv.
__global__ __launch_bounds__(256, 2) void ct_pre(
    const float* __restrict__ x, const float* __restrict__ temb,
    const float* __restrict__ trw, const float* __restrict__ trb,
    const float* __restrict__ tiw, const float* __restrict__ tib,
    const float* __restrict__ stw, const float* __restrict__ stb,
    const float* __restrict__ scw, const float* __restrict__ swr,
    const float* __restrict__ swi, const float* __restrict__ c1w,
    const float* __restrict__ c1b, const float* __restrict__ sweight,
    float2* __restrict__ A2, float* __restrict__ Mm,
    float* __restrict__ bias2, float* __restrict__ tv,
    float* __restrict__ ftmA_re, float* __restrict__ ftmA_im,
    float* __restrict__ ftmB_re, float* __restrict__ ftmB_im) {
  __shared__ __align__(16) char sm[34304];
  int vb = blockIdx.x;
  int tid = threadIdx.x;
  if (vb < 255) wigner_block(vb, tid, sm);
  else if (vb < 767) {
    // XCD-pairing swizzle: mh pair sits 8 apart in linear id (same XCD on %8 round-robin),
    // so both read the same x half-tile through one L2.
    int u = vb - 255;                        // 0..511
    int g = u >> 4, mh = (u >> 3) & 1, s = u & 7;
    int tp = g * 8 + s;                      // 0..255
    dft_block(tp >> 1, tp & 1, mh, tid, x, ftmA_re, ftmA_im, ftmB_re, ftmB_im, sm);
  }
  else if (vb < 831) a2_block(vb - 767, tid, temb, trw, trb, tiw, tib, scw, swr, swi, A2, sm);
  else mstv_block(tid, temb, stw, stb, c1w, c1b, sweight, tv, Mm, bias2, sm);
}

// ======================= ct_mid: fused projf + mix + proji, per (mm, oh), block 1024 =======================
// grid 256 linear: mm = (b>>4)*8 + (b&7), oh = (b>>3)&1; mm==127 -> idle.
// oh-siblings are 8 apart (same XCD): second gets staging from L2.
__global__ __launch_bounds__(1024, 1) void ct_mid(
    const float* __restrict__ fAre, const float* __restrict__ fAim,
    const float* __restrict__ fBre, const float* __restrict__ fBim,
    const float2* __restrict__ A2, const float* __restrict__ Mm,
    const float* __restrict__ scb, const float* __restrict__ bias2,
    float* __restrict__ fos_re, float* __restrict__ fos_im,
    float* __restrict__ foh_re, float* __restrict__ foh_im) {
  __shared__ __align__(16) char sm[98304];
  int b = blockIdx.x;
  int mm = (b >> 4) * 8 + (b & 7);
  int oh = (b >> 3) & 1;
  if (mm > 126) return;
  int tid = threadIdx.x;
  int mi = (mm >= 63) ? (mm - 63) : (63 - mm);
  float csign = (mm >= 63) ? 1.0f : -1.0f;

  float* fre_s = (float*)(sm);             // [128][64] 32 KB
  float* fim_s = (float*)(sm + 32768);     // [128][64] 32 KB
  float* Dt    = (float*)(sm + 65536);     // [128][64] 32 KB ([t][l])
  float* flm_re = (float*)(sm);            // [64][68] 17408 B (overlay)
  float* flm_im = (float*)(sm + 17408);    // [64][68]
  float* slS    = (float*)(sm + 34816);    // [64]
  float* sS_re  = (float*)(sm + 35072);    // [64][34]
  float* sS_im  = (float*)(sm + 43776);
  float* hS_re  = (float*)(sm + 52480);
  float* hS_im  = (float*)(sm + 61184);
  float* Dsh    = (float*)(sm + 69888);    // [64][64] 16 KB

  // Stage A staging: all streams fully contiguous (32 KB each)
  {
    const float4* pAre = (const float4*)fAre + (size_t)mi * 2048;
    const float4* pBre = (const float4*)fBre + (size_t)mi * 2048;
    const float4* pAim = (const float4*)fAim + (size_t)mi * 2048;
    const float4* pBim = (const float4*)fBim + (size_t)mi * 2048;
    const float4* pD = (const float4*)g_Deff + (size_t)mm * 2048;
    for (int e = tid; e < 2048; e += 1024) {
      float4 a = pAre[e];
      float4 bb = pBre[e];
      float4 a2i = pAim[e];
      float4 b2i = pBim[e];
      float4 d4 = pD[e];
      ((float4*)fre_s)[e] = make_float4(a.x + bb.x, a.y + bb.y, a.z + bb.z, a.w + bb.w);
      ((float4*)fim_s)[e] = make_float4(csign * (a2i.x + b2i.x), csign * (a2i.y + b2i.y),
                                        csign * (a2i.z + b2i.z), csign * (a2i.w + b2i.w));
      ((float4*)Dt)[e] = d4;
    }
  }
  __syncthreads();
  int cg = tid & 15, lw = tid >> 4;
  float ar[4], ai[4], sl = 0.f;
#pragma unroll
  for (int q = 0; q < 4; ++q) { ar[q] = 0.f; ai[q] = 0.f; }
#pragma unroll 4
  for (int k = 0; k < 128; ++k) {
    float4 fr4 = *(const float4*)&fre_s[k * 64 + cg * 4];
    float4 fi4 = *(const float4*)&fim_s[k * 64 + cg * 4];
    float dv = Dt[k * 64 + lw];
    float frv[4] = {fr4.x, fr4.y, fr4.z, fr4.w};
    float fiv[4] = {fi4.x, fi4.y, fi4.z, fi4.w};
    sl += dv;
#pragma unroll
    for (int q = 0; q < 4; ++q) {
      ar[q] = fmaf(dv, frv[q], ar[q]);
      ai[q] = fmaf(dv, fiv[q], ai[q]);
    }
  }
  __syncthreads();
  *(float4*)&flm_re[lw * 68 + cg * 4] = make_float4(ar[0], ar[1], ar[2], ar[3]);
  *(float4*)&flm_im[lw * 68 + cg * 4] = make_float4(ai[0], ai[1], ai[2], ai[3]);
  if (cg == 0) slS[lw] = sl;
  __syncthreads();

  {
    int lB = tid >> 4;
    int ov = tid & 15;
    int o0 = oh * 32 + ov * 2;
    float sr[2], si2[2], hr[2], hi2[2];
#pragma unroll
    for (int q = 0; q < 2; ++q) {
      sr[q] = scb[o0 + q]; si2[q] = 0.f; hr[q] = 0.f; hi2[q] = 0.f;
    }
#pragma unroll 2
    for (int i = 0; i < 64; ++i) {
      float fr = flm_re[lB * 68 + i];
      float fi = flm_im[lB * 68 + i];
      const float2* a2p = &A2[((size_t)lB * 64 + i) * 64 + o0];
      const float* mmp = &Mm[i * 64 + o0];
#pragma unroll
      for (int q = 0; q < 2; ++q) {
        float2 a = a2p[q];
        float mv = mmp[q];
        sr[q] = fmaf(fr, a.x, fmaf(-fi, a.y, sr[q]));
        si2[q] = fmaf(fr, a.y, fmaf(fi, a.x, si2[q]));
        hr[q] = fmaf(fr, mv, hr[q]);
        hi2[q] = fmaf(fi, mv, hi2[q]);
      }
    }
    if (mm == 63) {
      float sl63 = 255.0f * slS[lB];
#pragma unroll
      for (int q = 0; q < 2; ++q) hr[q] = fmaf(sl63, bias2[o0 + q], hr[q]);
    }
    int ob = ov * 2;
#pragma unroll
    for (int q = 0; q < 2; ++q) {
      sS_re[lB * 34 + ob + q] = sr[q];
      sS_im[lB * 34 + ob + q] = si2[q];
      hS_re[lB * 34 + ob + q] = hr[q];
      hS_im[lB * 34 + ob + q] = hi2[q];
    }
  }
  __syncthreads();

  for (int e = tid; e < 4096; e += 1024) {
    int r = e >> 6, tt = e & 63;
    Dsh[r * 64 + tt] = g_Dinv[((size_t)mm * 64 + r) * 64 + tt];
  }
  __syncthreads();
  {
    int cg2 = tid & 15, tg = tid >> 4;
    float as_r[2], as_i[2], ah_r[2], ah_i[2];
#pragma unroll
    for (int q = 0; q < 2; ++q) {
      as_r[q] = 0.f; as_i[q] = 0.f; ah_r[q] = 0.f; ah_i[q] = 0.f;
    }
#pragma unroll 4
    for (int l = 0; l < 64; ++l) {
      float dv = Dsh[l * 64 + tg];
      float2 s_r = *(const float2*)&sS_re[l * 34 + cg2 * 2];
      float2 s_i = *(const float2*)&sS_im[l * 34 + cg2 * 2];
      float2 h_r = *(const float2*)&hS_re[l * 34 + cg2 * 2];
      float2 h_i = *(const float2*)&hS_im[l * 34 + cg2 * 2];
      float srv[2] = {s_r.x, s_r.y}, siv[2] = {s_i.x, s_i.y};
      float hrv[2] = {h_r.x, h_r.y}, hiv[2] = {h_i.x, h_i.y};
#pragma unroll
      for (int q = 0; q < 2; ++q) {
        as_r[q] = fmaf(dv, srv[q], as_r[q]);
        as_i[q] = fmaf(dv, siv[q], as_i[q]);
        ah_r[q] = fmaf(dv, hrv[q], ah_r[q]);
        ah_i[q] = fmaf(dv, hiv[q], ah_i[q]);
      }
    }
    int c0 = oh * 32 + cg2 * 2;
    size_t ob = ((size_t)tg * 127 + mm) * 64 + c0;
    *(float2*)(fos_re + ob) = make_float2(as_r[0], as_r[1]);
    *(float2*)(fos_im + ob) = make_float2(as_i[0], as_i[1]);
    *(float2*)(foh_re + ob) = make_float2(ah_r[0], ah_r[1]);
    *(float2*)(foh_im + ob) = make_float2(ah_i[0], ah_i[1]);
  }
}

// ======================= ct_tail: fused inverse-DFT (full K) + epilogue =======================
// grid 256 linear: t = (b>>5)*8 + (b&7), q = (b>>3)&3. q-quad sits 8 apart -> same XCD,
// so the 4 blocks sharing a t-tile read it through one L2.
__global__ __launch_bounds__(1024, 1) void ct_tail(
    const float* __restrict__ fos_re, const float* __restrict__ fos_im,
    const float* __restrict__ foh_re, const float* __restrict__ foh_im,
    const float* __restrict__ c2w, const float* __restrict__ c2b,
    const float* __restrict__ tv, const float* __restrict__ lns,
    const float* __restrict__ lnb, float* __restrict__ out) {
  __shared__ __align__(16) char smc[32768];
  float* fsr = (float*)(smc);
  float* fsi = (float*)(smc + 8192);
  float* fhr = (float*)(smc + 16384);
  float* fhi = (float*)(smc + 24576);
  float* hS   = (float*)(smc);           // [32][66] = 8448 B (overlay)
  float* c2wS = (float*)(smc + 8448);    // [64][64] = 16384 B

  int b = blockIdx.x;
  int t = (b >> 5) * 8 + (b & 7);
  int q = (b >> 3) & 3;
  int tid = threadIdx.x;
  int gpg = tid >> 5;        // 0..31
  int cg = tid & 31;         // 0..31
  int gp = q * 32 + gpg;     // 0..127 (127 invalid)
  bool valid = (gp < 127);
  int gpc = valid ? gp : 126;

  float rcv, rsv;
  __sincosf(CN127F * (float)gpc, &rsv, &rcv);
  float wcv, wsv;
  int r0 = (-63 * gpc) % 127;
  __sincosf(CN127F * (float)r0, &wsv, &wcv);

  float xacc[2] = {0.f, 0.f}, hacc[2] = {0.f, 0.f};
  for (int k0 = 0; k0 < 127; k0 += 32) {
    int kn = (127 - k0 < 32) ? 127 - k0 : 32;
    __syncthreads();
    for (int e = tid; e < 2048; e += 1024) {
      int a = e >> 9, rr = (e >> 4) & 31, c4 = e & 15;
      if (rr < kn) {
        size_t idx = ((size_t)t * 127 + k0 + rr) * 16 + c4;
        float4 v;
        float* dst;
        if (a == 0)      { v = ((const float4*)fos_re)[idx]; dst = fsr; }
        else if (a == 1) { v = ((const float4*)fos_im)[idx]; dst = fsi; }
        else if (a == 2) { v = ((const float4*)foh_re)[idx]; dst = fhr; }
        else             { v = ((const float4*)foh_im)[idx]; dst = fhi; }
        ((float4*)dst)[rr * 16 + c4] = v;
      }
    }
    __syncthreads();
#pragma unroll 2
    for (int k = 0; k < kn; ++k) {
      float2 sr = *(const float2*)&fsr[k * 64 + cg * 2];
      float2 si = *(const float2*)&fsi[k * 64 + cg * 2];
      float2 hr = *(const float2*)&fhr[k * 64 + cg * 2];
      float2 hi = *(const float2*)&fhi[k * 64 + cg * 2];
      xacc[0] = fmaf(sr.x, wcv, xacc[0]); xacc[0] = fmaf(si.x, -wsv, xacc[0]);
      xacc[1] = fmaf(sr.y, wcv, xacc[1]); xacc[1] = fmaf(si.y, -wsv, xacc[1]);
      hacc[0] = fmaf(hr.x, wcv, hacc[0]); hacc[0] = fmaf(hi.x, -wsv, hacc[0]);
      hacc[1] = fmaf(hr.y, wcv, hacc[1]); hacc[1] = fmaf(hi.y, -wsv, hacc[1]);
      float nw = wcv * rcv - wsv * rsv;
      wsv = fmaf(wcv, rsv, wsv * rcv);
      wcv = nw;
    }
  }
  __syncthreads();  // staging dead; epilogue overlays

  if (valid) {
    hS[gpg * 66 + cg * 2] = hacc[0];
    hS[gpg * 66 + cg * 2 + 1] = hacc[1];
  }
  for (int e = tid; e < 1024; e += 1024)
    ((float4*)c2wS)[e] = ((const float4*)c2w)[e];
  __syncthreads();

  if (valid) {
    int c0 = cg * 2;
    float a0 = c2b[c0] + tv[64 + c0];
    float a1 = c2b[c0 + 1] + tv[64 + c0 + 1];
#pragma unroll 8
    for (int i = 0; i < 64; ++i) {
      float hvi = hS[gpg * 66 + i];
      a0 = fmaf(hvi, c2wS[i * 64 + c0], a0);
      a1 = fmaf(hvi, c2wS[i * 64 + c0 + 1], a1);
    }
    float ssl = xacc[0] * xacc[0] + xacc[1] * xacc[1];
#pragma unroll
    for (int off = 16; off > 0; off >>= 1) ssl += __shfl_xor(ssl, off, 64);
    float inv = 1.0f / (sqrtf(ssl) + 1e-6f);
    float y0 = xacc[0] * inv + a0;
    float y1 = xacc[1] * inv + a1;
    float g0 = gelu_tanh(y0), g1 = gelu_tanh(y1);
    float ms = g0 + g1;
#pragma unroll
    for (int off = 16; off > 0; off >>= 1) ms += __shfl_xor(ms, off, 64);
    float mu = ms * (1.0f / 64.0f);
    float d0 = g0 - mu, d1 = g1 - mu;
    float vs = d0 * d0 + d1 * d1;
#pragma unroll
    for (int off = 16; off > 0; off >>= 1) vs += __shfl_xor(vs, off, 64);
    float rstd = rsqrtf(vs * (1.0f / 64.0f) + 1e-6f);
    size_t ob = ((size_t)t * 127 + gp) * 64 + c0;
    out[ob] = d0 * rstd * lns[c0] + lnb[c0];
    out[ob + 1] = d1 * rstd * lns[c0 + 1] + lnb[c0 + 1];
  }
  if (blockIdx.x == 0 && tid == 0)
    __hip_atomic_store(&g_wig_done, 1, __ATOMIC_RELAXED, __HIP_MEMORY_SCOPE_AGENT);
}

// ---------------- host launcher ----------------
extern "C" void kernel_launch(void* const* d_in, const int* in_sizes, int n_in,
                              void* d_out, int out_size, void* d_ws, size_t ws_size,
                              hipStream_t stream) {
  const float* x = (const float*)d_in[0];
  const float* temb = (const float*)d_in[1];
  const float* scw = (const float*)d_in[2];
  const float* scb = (const float*)d_in[3];
  const float* swr = (const float*)d_in[4];
  const float* swi = (const float*)d_in[5];
  const float* strw = (const float*)d_in[6];
  const float* strb = (const float*)d_in[7];
  const float* stiw = (const float*)d_in[8];
  const float* stib = (const float*)d_in[9];
  const float* c1w = (const float*)d_in[10];
  const float* c1b = (const float*)d_in[11];
  const float* stw = (const float*)d_in[12];
  const float* stb = (const float*)d_in[13];
  const float* sweight = (const float*)d_in[14];
  const float* c2w = (const float*)d_in[15];
  const float* c2b = (const float*)d_in[16];
  const float* lns = (const float*)d_in[17];
  const float* lnb = (const float*)d_in[18];
  float* out = (float*)d_out;

  char* base = (char*)d_ws;
  size_t off = 0;
  auto alloc = [&](size_t bytes) -> void* {
    void* p = base + off;
    off += (bytes + 255) & ~(size_t)255;
    return p;
  };
  float* tv = (float*)alloc(128 * sizeof(float));
  float* Mm = (float*)alloc(4096 * sizeof(float));
  float* bias2 = (float*)alloc(64 * sizeof(float));
  float2* A2 = (float2*)alloc(262144 * sizeof(float2));
  float* fos_re = (float*)alloc(520192 * sizeof(float));  // [t<64][mm][c]
  float* fos_im = (float*)alloc(520192 * sizeof(float));
  float* foh_re = (float*)alloc(520192 * sizeof(float));
  float* foh_im = (float*)alloc(520192 * sizeof(float));
  float* ftmA_re = (float*)alloc(524288 * sizeof(float)); // [mi<64][t<128][c]
  float* ftmA_im = (float*)alloc(524288 * sizeof(float));
  float* ftmB_re = (float*)alloc(524288 * sizeof(float));
  float* ftmB_im = (float*)alloc(524288 * sizeof(float));
  if (off > ws_size) return;  // workspace too small -> visible failure

  hipLaunchKernelGGL(ct_pre, dim3(832), dim3(256), 0, stream,
                     x, temb, strw, strb, stiw, stib, stw, stb,
                     scw, swr, swi, c1w, c1b, sweight,
                     A2, Mm, bias2, tv,
                     ftmA_re, ftmA_im, ftmB_re, ftmB_im);
  hipLaunchKernelGGL(ct_mid, dim3(256), dim3(1024), 0, stream,
                     ftmA_re, ftmA_im, ftmB_re, ftmB_im,
                     A2, Mm, scb, bias2,
                     fos_re, fos_im, foh_re, foh_im);
  hipLaunchKernelGGL(ct_tail, dim3(256), dim3(1024), 0, stream,
                     fos_re, fos_im, foh_re, foh_im,
                     c2w, c2b, tv, lns, lnb, out);
}